// Round 1
// baseline (102.118 us; speedup 1.0000x reference)
//
#include <hip/hip_runtime.h>

// Gaussian3D covariance: cov[n] = R(q_n) * diag(exp(ls_n)) * R(q_n)^T
// Memory-bound map: 28 B in + 36 B out per point.

constexpr int BLOCK = 256;

__global__ __launch_bounds__(BLOCK) void gauss_cov_kernel(
    const float4* __restrict__ quat,   // [n] (qw,qx,qy,qz)
    const float*  __restrict__ logs,   // [n*3]
    float*        __restrict__ out,    // [n*9]
    int n)
{
    __shared__ float lds[BLOCK * 9];
    const int tid = threadIdx.x;

    for (long long base = (long long)blockIdx.x * BLOCK; base < n;
         base += (long long)gridDim.x * BLOCK) {
        const long long i = base + tid;
        const bool valid = (i < n);

        float c00 = 0.f, c01 = 0.f, c02 = 0.f, c11 = 0.f, c12 = 0.f, c22 = 0.f;
        if (valid) {
            float4 q = quat[i];
            float s0 = __expf(logs[3 * i + 0]);
            float s1 = __expf(logs[3 * i + 1]);
            float s2 = __expf(logs[3 * i + 2]);

            float inv = rsqrtf(q.x * q.x + q.y * q.y + q.z * q.z + q.w * q.w);
            float qw = q.x * inv, qx = q.y * inv, qy = q.z * inv, qz = q.w * inv;

            float r00 = 1.0f - 2.0f * (qy * qy + qz * qz);
            float r01 = 2.0f * (qx * qy - qz * qw);
            float r02 = 2.0f * (qx * qz + qy * qw);
            float r10 = 2.0f * (qx * qy + qz * qw);
            float r11 = 1.0f - 2.0f * (qx * qx + qz * qz);
            float r12 = 2.0f * (qy * qz - qx * qw);
            float r20 = 2.0f * (qx * qz - qy * qw);
            float r21 = 2.0f * (qy * qz + qx * qw);
            float r22 = 1.0f - 2.0f * (qx * qx + qy * qy);

            float m00 = r00 * s0, m01 = r01 * s1, m02 = r02 * s2;
            float m10 = r10 * s0, m11 = r11 * s1, m12 = r12 * s2;
            float m20 = r20 * s0, m21 = r21 * s1, m22 = r22 * s2;

            c00 = m00 * r00 + m01 * r01 + m02 * r02;
            c01 = m00 * r10 + m01 * r11 + m02 * r12;
            c02 = m00 * r20 + m01 * r21 + m02 * r22;
            c11 = m10 * r10 + m11 * r11 + m12 * r12;
            c12 = m10 * r20 + m11 * r21 + m12 * r22;
            c22 = m20 * r20 + m21 * r21 + m22 * r22;
        }

        // Stage per-thread 9 results (stride-9 across lanes: gcd(9,32)=1 -> no
        // bank conflicts beyond the free 2-way), then write unit-stride.
        float* l = &lds[tid * 9];
        l[0] = c00; l[1] = c01; l[2] = c02;
        l[3] = c01; l[4] = c11; l[5] = c12;
        l[6] = c02; l[7] = c12; l[8] = c22;
        __syncthreads();

        const long long ob = base * 9;           // block-tile start in out[]
        const long long total = (long long)n * 9;
#pragma unroll
        for (int k = 0; k < 9; ++k) {
            long long idx = ob + tid + k * BLOCK;
            if (idx < total) out[idx] = lds[tid + k * BLOCK];
        }
        __syncthreads();
    }
}

extern "C" void kernel_launch(void* const* d_in, const int* in_sizes, int n_in,
                              void* d_out, int out_size, void* d_ws, size_t ws_size,
                              hipStream_t stream) {
    const float4* quat = (const float4*)d_in[0];
    const float*  logs = (const float*)d_in[1];
    float*        out  = (float*)d_out;
    int n = in_sizes[0] / 4;   // 8,000,000

    int nblocks = (n + BLOCK - 1) / BLOCK;
    if (nblocks > 2048) nblocks = 2048;   // grid-stride; 8 blocks/CU = 32 waves/CU

    gauss_cov_kernel<<<dim3(nblocks), dim3(BLOCK), 0, stream>>>(quat, logs, out, n);
}

// Round 2
// 92.945 us; speedup vs baseline: 1.0987x; 1.0987x over previous
//
#include <hip/hip_runtime.h>

// Gaussian3D covariance: cov[n] = R(q_n) * diag(exp(ls_n)) * R(q_n)^T
// Memory-bound map: 28 B in + 36 B out per point. Roofline ~81 us @6.3 TB/s.
//
// Structure: 1 thread = 1 point. Wave-private LDS transpose (no block
// barriers; cross-lane sharing stays within the 64-lane wave, which is
// ordered by in-order wave-wide ds ops + lgkmcnt) turns the stride-9
// output into fully-coalesced dwordx4 stores.

constexpr int BLOCK = 256;
constexpr int WAVES = BLOCK / 64;

__global__ __launch_bounds__(BLOCK) void gauss_cov_kernel(
    const float4* __restrict__ quat,   // [n] (qw,qx,qy,qz)
    const float*  __restrict__ logs,   // [n*3]
    float*        __restrict__ out,    // [n*9]
    int n)
{
    __shared__ float lds[WAVES][64 * 9];   // 9216 B, wave-private regions
    const int tid  = threadIdx.x;
    const int lane = tid & 63;
    const int w    = tid >> 6;

    const long long p0 = (long long)blockIdx.x * BLOCK + (long long)w * 64;
    const long long i  = p0 + lane;

    float c00 = 0.f, c01 = 0.f, c02 = 0.f, c11 = 0.f, c12 = 0.f, c22 = 0.f;
    if (i < n) {
        float4 q = quat[i];
        float s0 = __expf(logs[3 * i + 0]);
        float s1 = __expf(logs[3 * i + 1]);
        float s2 = __expf(logs[3 * i + 2]);

        float inv = rsqrtf(q.x * q.x + q.y * q.y + q.z * q.z + q.w * q.w);
        float qw = q.x * inv, qx = q.y * inv, qy = q.z * inv, qz = q.w * inv;

        float r00 = 1.0f - 2.0f * (qy * qy + qz * qz);
        float r01 = 2.0f * (qx * qy - qz * qw);
        float r02 = 2.0f * (qx * qz + qy * qw);
        float r10 = 2.0f * (qx * qy + qz * qw);
        float r11 = 1.0f - 2.0f * (qx * qx + qz * qz);
        float r12 = 2.0f * (qy * qz - qx * qw);
        float r20 = 2.0f * (qx * qz - qy * qw);
        float r21 = 2.0f * (qy * qz + qx * qw);
        float r22 = 1.0f - 2.0f * (qx * qx + qy * qy);

        float m00 = r00 * s0, m01 = r01 * s1, m02 = r02 * s2;
        float m10 = r10 * s0, m11 = r11 * s1, m12 = r12 * s2;
        float m20 = r20 * s0, m21 = r21 * s1, m22 = r22 * s2;

        c00 = m00 * r00 + m01 * r01 + m02 * r02;
        c01 = m00 * r10 + m01 * r11 + m02 * r12;
        c02 = m00 * r20 + m01 * r21 + m02 * r22;
        c11 = m10 * r10 + m11 * r11 + m12 * r12;
        c12 = m10 * r20 + m11 * r21 + m12 * r22;
        c22 = m20 * r20 + m21 * r21 + m22 * r22;
    }

    // Stage: stride-9 word writes -> gcd(9,32)=1 -> 2 lanes/bank (free).
    float* L = &lds[w][0];
    L[lane * 9 + 0] = c00; L[lane * 9 + 1] = c01; L[lane * 9 + 2] = c02;
    L[lane * 9 + 3] = c01; L[lane * 9 + 4] = c11; L[lane * 9 + 5] = c12;
    L[lane * 9 + 6] = c02; L[lane * 9 + 7] = c12; L[lane * 9 + 8] = c22;

    // Wave-synchronous ordering: ds ops are wave-wide and in-order; the
    // compiler inserts lgkmcnt waits for the may-alias read below. Pin
    // compiler ordering explicitly.
    __builtin_amdgcn_wave_barrier();
    asm volatile("" ::: "memory");

    // Drain: 144 float4 per wave, fully coalesced 16B/lane stores.
    const float4* Lf4 = (const float4*)L;
    const long long e0    = p0 * 9;                 // 16B-aligned (p0 % 64 == 0)
    const long long total = (long long)n * 9;
#pragma unroll
    for (int k = 0; k < 3; ++k) {
        int m = lane + k * 64;
        if (m < 144) {
            long long e = e0 + (long long)m * 4;
            if (e + 4 <= total) {
                *(float4*)(out + e) = Lf4[m];
            } else if (e < total) {
                float4 v = Lf4[m];
                const float vv[4] = {v.x, v.y, v.z, v.w};
                for (int j = 0; j < 4 && e + j < total; ++j) out[e + j] = vv[j];
            }
        }
    }
}

extern "C" void kernel_launch(void* const* d_in, const int* in_sizes, int n_in,
                              void* d_out, int out_size, void* d_ws, size_t ws_size,
                              hipStream_t stream) {
    const float4* quat = (const float4*)d_in[0];
    const float*  logs = (const float*)d_in[1];
    float*        out  = (float*)d_out;
    int n = in_sizes[0] / 4;   // 8,000,000

    int nblocks = (n + BLOCK - 1) / BLOCK;  // exact cover, no grid-stride loop
    gauss_cov_kernel<<<dim3(nblocks), dim3(BLOCK), 0, stream>>>(quat, logs, out, n);
}

// Round 4
// 77.023 us; speedup vs baseline: 1.3258x; 1.2067x over previous
//
#include <hip/hip_runtime.h>

// Gaussian3D covariance: cov[n] = R(q_n) * diag(exp(ls_n)) * R(q_n)^T
// Memory-bound map: 28 B in + 36 B out per point.
//
// R4: non-temporal output stores (via native ext_vector_type, since the
// builtin rejects HIP_vector_type). Inputs (224 MB) fit in the 256 MB
// Infinity Cache; keep the 288 MB write-once output stream from evicting
// them so graph replays read inputs from L3.

typedef float f32x4 __attribute__((ext_vector_type(4)));

constexpr int BLOCK = 256;
constexpr int WAVES = BLOCK / 64;

__global__ __launch_bounds__(BLOCK) void gauss_cov_kernel(
    const float4* __restrict__ quat,   // [n] (qw,qx,qy,qz)
    const float*  __restrict__ logs,   // [n*3]
    float*        __restrict__ out,    // [n*9]
    int n)
{
    __shared__ float lds[WAVES][64 * 9];   // 9216 B, wave-private regions
    const int tid  = threadIdx.x;
    const int lane = tid & 63;
    const int w    = tid >> 6;

    const long long p0 = (long long)blockIdx.x * BLOCK + (long long)w * 64;
    const long long i  = p0 + lane;

    float c00 = 0.f, c01 = 0.f, c02 = 0.f, c11 = 0.f, c12 = 0.f, c22 = 0.f;
    if (i < n) {
        float4 q = quat[i];
        float s0 = __expf(logs[3 * i + 0]);
        float s1 = __expf(logs[3 * i + 1]);
        float s2 = __expf(logs[3 * i + 2]);

        float inv = rsqrtf(q.x * q.x + q.y * q.y + q.z * q.z + q.w * q.w);
        float qw = q.x * inv, qx = q.y * inv, qy = q.z * inv, qz = q.w * inv;

        float r00 = 1.0f - 2.0f * (qy * qy + qz * qz);
        float r01 = 2.0f * (qx * qy - qz * qw);
        float r02 = 2.0f * (qx * qz + qy * qw);
        float r10 = 2.0f * (qx * qy + qz * qw);
        float r11 = 1.0f - 2.0f * (qx * qx + qz * qz);
        float r12 = 2.0f * (qy * qz - qx * qw);
        float r20 = 2.0f * (qx * qz - qy * qw);
        float r21 = 2.0f * (qy * qz + qx * qw);
        float r22 = 1.0f - 2.0f * (qx * qx + qy * qy);

        float m00 = r00 * s0, m01 = r01 * s1, m02 = r02 * s2;
        float m10 = r10 * s0, m11 = r11 * s1, m12 = r12 * s2;
        float m20 = r20 * s0, m21 = r21 * s1, m22 = r22 * s2;

        c00 = m00 * r00 + m01 * r01 + m02 * r02;
        c01 = m00 * r10 + m01 * r11 + m02 * r12;
        c02 = m00 * r20 + m01 * r21 + m02 * r22;
        c11 = m10 * r10 + m11 * r11 + m12 * r12;
        c12 = m10 * r20 + m11 * r21 + m12 * r22;
        c22 = m20 * r20 + m21 * r21 + m22 * r22;
    }

    // Stage: stride-9 word writes -> gcd(9,32)=1 -> 2 lanes/bank (free).
    float* L = &lds[w][0];
    L[lane * 9 + 0] = c00; L[lane * 9 + 1] = c01; L[lane * 9 + 2] = c02;
    L[lane * 9 + 3] = c01; L[lane * 9 + 4] = c11; L[lane * 9 + 5] = c12;
    L[lane * 9 + 6] = c02; L[lane * 9 + 7] = c12; L[lane * 9 + 8] = c22;

    // Wave-synchronous: ds ops are wave-wide and in-order; compiler inserts
    // lgkmcnt for the read below. Pin ordering explicitly.
    __builtin_amdgcn_wave_barrier();
    asm volatile("" ::: "memory");

    // Drain: 144 float4 per wave, coalesced 16B/lane non-temporal stores.
    const f32x4* Lf4 = (const f32x4*)L;
    const long long e0    = p0 * 9;                 // 16B-aligned (p0 % 64 == 0)
    const long long total = (long long)n * 9;
#pragma unroll
    for (int k = 0; k < 3; ++k) {
        int m = lane + k * 64;
        if (m < 144) {
            long long e = e0 + (long long)m * 4;
            if (e + 4 <= total) {
                __builtin_nontemporal_store(Lf4[m], (f32x4*)(out + e));
            } else if (e < total) {
                f32x4 v = Lf4[m];
                for (int j = 0; j < 4 && e + j < total; ++j)
                    __builtin_nontemporal_store(v[j], out + e + j);
            }
        }
    }
}

extern "C" void kernel_launch(void* const* d_in, const int* in_sizes, int n_in,
                              void* d_out, int out_size, void* d_ws, size_t ws_size,
                              hipStream_t stream) {
    const float4* quat = (const float4*)d_in[0];
    const float*  logs = (const float*)d_in[1];
    float*        out  = (float*)d_out;
    int n = in_sizes[0] / 4;   // 8,000,000

    int nblocks = (n + BLOCK - 1) / BLOCK;  // exact cover, no grid-stride loop
    gauss_cov_kernel<<<dim3(nblocks), dim3(BLOCK), 0, stream>>>(quat, logs, out, n);
}

// Round 5
// 76.390 us; speedup vs baseline: 1.3368x; 1.0083x over previous
//
#include <hip/hip_runtime.h>

// Gaussian3D covariance: cov[n] = R(q_n) * diag(exp(ls_n)) * R(q_n)^T
// Memory-bound map: 28 B in + 36 B out per point.
//
// R5: output stores via inline asm "global_store_dwordx4 ... nt sc1" —
// non-temporal + system scope, the strongest stream/bypass hint on gfx950.
// Goal: keep the 288 MB write-once stream out of the 256 MB Infinity Cache
// so the 224 MB input set stays L3-resident across graph replays.

typedef float f32x4 __attribute__((ext_vector_type(4)));

constexpr int BLOCK = 256;
constexpr int WAVES = BLOCK / 64;

__device__ __forceinline__ void store_nt_bypass(float* addr, f32x4 v) {
    asm volatile("global_store_dwordx4 %0, %1, off nt sc1"
                 :: "v"(addr), "v"(v) : "memory");
}

__global__ __launch_bounds__(BLOCK) void gauss_cov_kernel(
    const float4* __restrict__ quat,   // [n] (qw,qx,qy,qz)
    const float*  __restrict__ logs,   // [n*3]
    float*        __restrict__ out,    // [n*9]
    int n)
{
    __shared__ float lds[WAVES][64 * 9];   // 9216 B, wave-private regions
    const int tid  = threadIdx.x;
    const int lane = tid & 63;
    const int w    = tid >> 6;

    const long long p0 = (long long)blockIdx.x * BLOCK + (long long)w * 64;
    const long long i  = p0 + lane;

    float c00 = 0.f, c01 = 0.f, c02 = 0.f, c11 = 0.f, c12 = 0.f, c22 = 0.f;
    if (i < n) {
        float4 q = quat[i];
        float s0 = __expf(logs[3 * i + 0]);
        float s1 = __expf(logs[3 * i + 1]);
        float s2 = __expf(logs[3 * i + 2]);

        float inv = rsqrtf(q.x * q.x + q.y * q.y + q.z * q.z + q.w * q.w);
        float qw = q.x * inv, qx = q.y * inv, qy = q.z * inv, qz = q.w * inv;

        float r00 = 1.0f - 2.0f * (qy * qy + qz * qz);
        float r01 = 2.0f * (qx * qy - qz * qw);
        float r02 = 2.0f * (qx * qz + qy * qw);
        float r10 = 2.0f * (qx * qy + qz * qw);
        float r11 = 1.0f - 2.0f * (qx * qx + qz * qz);
        float r12 = 2.0f * (qy * qz - qx * qw);
        float r20 = 2.0f * (qx * qz - qy * qw);
        float r21 = 2.0f * (qy * qz + qx * qw);
        float r22 = 1.0f - 2.0f * (qx * qx + qy * qy);

        float m00 = r00 * s0, m01 = r01 * s1, m02 = r02 * s2;
        float m10 = r10 * s0, m11 = r11 * s1, m12 = r12 * s2;
        float m20 = r20 * s0, m21 = r21 * s1, m22 = r22 * s2;

        c00 = m00 * r00 + m01 * r01 + m02 * r02;
        c01 = m00 * r10 + m01 * r11 + m02 * r12;
        c02 = m00 * r20 + m01 * r21 + m02 * r22;
        c11 = m10 * r10 + m11 * r11 + m12 * r12;
        c12 = m10 * r20 + m11 * r21 + m12 * r22;
        c22 = m20 * r20 + m21 * r21 + m22 * r22;
    }

    // Stage: stride-9 word writes -> gcd(9,32)=1 -> 2 lanes/bank (free).
    float* L = &lds[w][0];
    L[lane * 9 + 0] = c00; L[lane * 9 + 1] = c01; L[lane * 9 + 2] = c02;
    L[lane * 9 + 3] = c01; L[lane * 9 + 4] = c11; L[lane * 9 + 5] = c12;
    L[lane * 9 + 6] = c02; L[lane * 9 + 7] = c12; L[lane * 9 + 8] = c22;

    // Wave-synchronous: ds ops are wave-wide and in-order; compiler inserts
    // lgkmcnt for the read below. Pin ordering explicitly.
    __builtin_amdgcn_wave_barrier();
    asm volatile("" ::: "memory");

    // Drain: 144 float4 per wave, coalesced 16B/lane streaming stores.
    const f32x4* Lf4 = (const f32x4*)L;
    const long long e0    = p0 * 9;                 // 16B-aligned (p0 % 64 == 0)
    const long long total = (long long)n * 9;
#pragma unroll
    for (int k = 0; k < 3; ++k) {
        int m = lane + k * 64;
        if (m < 144) {
            long long e = e0 + (long long)m * 4;
            if (e + 4 <= total) {
                store_nt_bypass(out + e, Lf4[m]);
            } else if (e < total) {
                f32x4 v = Lf4[m];
                for (int j = 0; j < 4 && e + j < total; ++j)
                    __builtin_nontemporal_store(v[j], out + e + j);
            }
        }
    }
}

extern "C" void kernel_launch(void* const* d_in, const int* in_sizes, int n_in,
                              void* d_out, int out_size, void* d_ws, size_t ws_size,
                              hipStream_t stream) {
    const float4* quat = (const float4*)d_in[0];
    const float*  logs = (const float*)d_in[1];
    float*        out  = (float*)d_out;
    int n = in_sizes[0] / 4;   // 8,000,000

    int nblocks = (n + BLOCK - 1) / BLOCK;  // exact cover, no grid-stride loop
    gauss_cov_kernel<<<dim3(nblocks), dim3(BLOCK), 0, stream>>>(quat, logs, out, n);
}